// Round 12
// baseline (3139.274 us; speedup 1.0000x reference)
//
#include <hip/hip_runtime.h>
#include <math.h>

#define NSTEPS 200
#define NT     512          // 8 waves; each wave owns 16 output cols
#define BR     64
#define SQDT_F 0.07071067811865475f
#define DT_F   0.005f
#define LOSCL  4096.0f            // 2^12
#define LOINV  2.44140625e-4f     // 2^-12

typedef float  f32x4 __attribute__((ext_vector_type(4)));
typedef short  s16x8 __attribute__((ext_vector_type(8)));
typedef _Float16 h16x8 __attribute__((ext_vector_type(8)));
typedef unsigned short u16;
typedef unsigned short us4 __attribute__((ext_vector_type(4)));

// prepacked weight offsets in u16 units (each 128x128 matrix = 32768 u16 as hi/lo frags)
#define ENC_OFF 0
#define W1_OFF  32768
#define W2_OFF  65536
#define WG0_OFF 98304
#define WG1_OFF 131072
#define DEC_OFF 163840
#define WPK_TOT 196608

// ---- fp16 scaled two-term split: x ~= hi + lo*2^-12, |err| <= ~2^-23 |x| ----
__device__ __forceinline__ u16 f2h(float v) {
    _Float16 h = (_Float16)v;                       // v_cvt_f16_f32, RNE
    return __builtin_bit_cast(u16, h);
}
__device__ __forceinline__ float h2f(u16 u) {
    return (float)__builtin_bit_cast(_Float16, u);
}
__device__ __forceinline__ u16 split_hi(float v) { return f2h(v); }
__device__ __forceinline__ u16 split_lo(float v, u16 hi) {
    return f2h((v - h2f(hi)) * LOSCL);              // v-hi exact in fp32; *2^12 exact
}
__device__ __forceinline__ float gelu_exact(float x) {
    // exact erf GELU: approx GELU re-rolls the chaotic trajectory (rounds 2/3).
    return 0.5f * x * (1.0f + erff(x * 0.70710678118654752f));
}

// MFMA via builtin: compiler models hazards (r6/r7 inline-asm MFMA NaN'd).
__device__ __forceinline__ void mfma16(f32x4& d, s16x8 a, s16x8 b) {
    d = __builtin_amdgcn_mfma_f32_16x16x32_f16(
            __builtin_bit_cast(h16x8, a), __builtin_bit_cast(h16x8, b), d, 0, 0, 0);
}
__device__ __forceinline__ s16x8 ldf(const u16* p) {
    return *reinterpret_cast<const s16x8*>(p);
}

// LDS swizzle: rows are 256 B apart (bank-aligned), so chunk XOR must spread
// rows 4 AND 8 apart across banks. row-bit3 folds into chunk-bit1:
// r11's (row&7) XOR left rows 8 apart colliding -> 4-way scalar conflicts.
__device__ __forceinline__ int swz(int row) {
    return (row & 7) ^ ((row & 8) >> 2);
}

// ---------------- weight prepack: fp32 -> fp16 hi / scaled-lo fragments ----------------
// frag layout: base + ((nt*4 + kc)*2 + term)*512 + lane*8 + i   (u16 units)
// element: B[k = kc*32 + (lane>>4)*8 + i][n = nt*16 + (lane&15)]
// sigma column-deinterleaved: WG0 = sig_w[:,0::2], WG1 = sig_w[:,1::2]
__global__ void prepack(const float* __restrict__ enc_w, const float* __restrict__ mu_w1,
                        const float* __restrict__ mu_w2, const float* __restrict__ sig_w,
                        const float* __restrict__ dec_w, u16* __restrict__ wpk)
{
    int u = blockIdx.x * 256 + threadIdx.x;
    if (u >= WPK_TOT) return;
    int mat  = u >> 15;
    int r    = u & 32767;
    int i    = r & 7;
    int lane = (r >> 3) & 63;
    int term = (r >> 9) & 1;
    int kc   = (r >> 10) & 3;
    int nt   = (r >> 12) & 7;
    int k = kc * 32 + (lane >> 4) * 8 + i;
    int n = nt * 16 + (lane & 15);
    float v;
    switch (mat) {
        case 0:  v = enc_w[k * 128 + n];         break;
        case 1:  v = mu_w1[k * 128 + n];         break;
        case 2:  v = mu_w2[k * 128 + n];         break;
        case 3:  v = sig_w[k * 256 + 2 * n];     break;
        case 4:  v = sig_w[k * 256 + 2 * n + 1]; break;
        default: v = dec_w[k * 128 + n];         break;
    }
    u16 hi = split_hi(v);
    wpk[u] = term ? split_lo(v, hi) : hi;
}

// ---------------- main fused SDE kernel ----------------
// r11 established: no resident weights (L2 B-frags), asm "+s" LICM-blocker,
// z in LDS only -> FETCH 36 MB, no spill. r12 adds:
//  - merged G1+sigma z-sweep in two mt-halves (z read once, not twice)
//  - swz() bank fix (scalar LDS ops 4-way -> 2-way)
__global__ __launch_bounds__(NT) void sde_mfma(
    const float* __restrict__ y, const float* __restrict__ noise,
    const float* __restrict__ enc_b, const float* __restrict__ mu_b1,
    const float* __restrict__ mu_b2, const float* __restrict__ sig_b,
    const float* __restrict__ dec_b, const u16* __restrict__ wpk,
    float* __restrict__ out, int Btot)
{
    __shared__ __align__(16) u16 zbh[8192];
    __shared__ __align__(16) u16 zbl[8192];
    __shared__ __align__(16) u16 hbh[8192];
    __shared__ __align__(16) u16 hbl[8192];
    __shared__ float nsb[2][128];

    const int tid  = threadIdx.x;
    const int lane = tid & 63, wid = tid >> 6;      // wid 0..7
    const int ln   = lane & 15, lg = lane >> 4;
    const size_t brow = (size_t)blockIdx.x * BR;

    const int n0 = wid * 16 + ln;                   // this thread's single col
    const float b10 = mu_b1[n0];
    const float b20 = mu_b2[n0];
    const float bg0 = sig_b[2 * n0];
    const float bg1 = sig_b[2 * n0 + 1];
    const int swzl = swz(ln);                       // A-read chunk swizzle (row&15 == ln)

    // ---- stage y into zb (fp16 hi/lo, swizzled) ----
    #pragma unroll
    for (int c = 0; c < 4; c++) {
        int q = c * NT + tid;                 // 0..2047
        int row = q >> 5, k4 = (q & 31) << 2;
        const float4 v = *reinterpret_cast<const float4*>(y + (brow + row) * 128 + k4);
        int idx = row * 128 + (((k4 >> 3) ^ swz(row)) << 3) + (k4 & 7);
        float vv[4] = {v.x, v.y, v.z, v.w};
        us4 hv, lv;
        #pragma unroll
        for (int e = 0; e < 4; e++) {
            u16 h = split_hi(vv[e]);
            u16 l = split_lo(vv[e], h);
            hv[e] = h; lv[e] = l;
        }
        *reinterpret_cast<us4*>(zbh + idx) = hv;
        *reinterpret_cast<us4*>(zbl + idx) = lv;
    }
    __syncthreads();

    // ---- encoder: z0 = gelu_exact(y @ enc_w + enc_b) ----
    float z0v[4][4];
    {
        const float be0 = enc_b[n0];
        f32x4 a0[4], a1[4];
        #pragma unroll
        for (int mt = 0; mt < 4; mt++) {
            a0[mt] = f32x4{be0, be0, be0, be0};
            a1[mt] = f32x4{0, 0, 0, 0};
        }
        #pragma unroll
        for (int kc = 0; kc < 4; kc++) {
            int fo = (((wid << 2) | kc) << 10) + (lane << 3);
            s16x8 bh = ldf(wpk + ENC_OFF + fo);
            s16x8 bl = ldf(wpk + ENC_OFF + fo + 512);
            #pragma unroll
            for (int mt = 0; mt < 4; mt++) {
                int idx = (mt * 16 + ln) * 128 + ((((kc << 2) | lg) ^ swzl) << 3);
                s16x8 ah = ldf(zbh + idx);
                s16x8 al = ldf(zbl + idx);
                mfma16(a0[mt], ah, bh);
                mfma16(a1[mt], al, bh);
                mfma16(a1[mt], ah, bl);
            }
        }
        #pragma unroll
        for (int mt = 0; mt < 4; mt++)
            #pragma unroll
            for (int r = 0; r < 4; r++)
                z0v[mt][r] = gelu_exact(fmaf(a1[mt][r], LOINV, a0[mt][r]));
    }
    __syncthreads();   // all y-tile reads done

    // write z0 into zb; stage noise for t=0
    #pragma unroll
    for (int mt = 0; mt < 4; mt++)
        #pragma unroll
        for (int r = 0; r < 4; r++) {
            int m = 16 * mt + 4 * lg + r;
            int idx = m * 128 + (((n0 >> 3) ^ swz(m)) << 3) + (n0 & 7);
            u16 h = split_hi(z0v[mt][r]);
            zbh[idx] = h;
            zbl[idx] = split_lo(z0v[mt][r], h);
        }
    if (tid < 128) nsb[0][tid] = noise[brow * 2 + tid];
    __syncthreads();

    // loop-opaque weight pointer: defeats LICM hoisting weight loads into
    // loop-carried registers (the scratch-spill source in r5-r10).
    const u16* wq = wpk;

    // ---- 200 Euler-Maruyama steps, 2 barriers each ----
    for (int t = 0; t < NSTEPS; t++) {
        asm volatile("" : "+s"(wq));
        {   // prefetch next step's noise into the other buffer
            int tn = (t + 1 < NSTEPS) ? (t + 1) : t;
            if (tid < 128) nsb[(t + 1) & 1][tid] = noise[((size_t)tn * Btot + brow) * 2 + tid];
        }
        // merged z-sweep: G1 + sigma share one A-read pass, in two mt-halves
        // (accum 48 f32/half keeps worst-phase demand under the 128-reg cap)
        float sdelta[4][4];
        const float* np = nsb[t & 1];
        #pragma unroll
        for (int half = 0; half < 2; half++) {
            f32x4 a0[2], a1[2], q0h[2], q0l[2], q1h[2], q1l[2];
            #pragma unroll
            for (int u = 0; u < 2; u++) {
                a0[u]  = f32x4{b10, b10, b10, b10};  a1[u]  = f32x4{0, 0, 0, 0};
                q0h[u] = f32x4{bg0, bg0, bg0, bg0};  q0l[u] = f32x4{0, 0, 0, 0};
                q1h[u] = f32x4{bg1, bg1, bg1, bg1};  q1l[u] = f32x4{0, 0, 0, 0};
            }
            #pragma unroll 2
            for (int kc = 0; kc < 4; kc++) {
                int fo = (((wid << 2) | kc) << 10) + (lane << 3);
                s16x8 b1h = ldf(wq + W1_OFF  + fo);
                s16x8 b1l = ldf(wq + W1_OFF  + fo + 512);
                s16x8 c0h = ldf(wq + WG0_OFF + fo);
                s16x8 c0l = ldf(wq + WG0_OFF + fo + 512);
                s16x8 c1h = ldf(wq + WG1_OFF + fo);
                s16x8 c1l = ldf(wq + WG1_OFF + fo + 512);
                #pragma unroll
                for (int u = 0; u < 2; u++) {
                    int idx = ((half * 2 + u) * 16 + ln) * 128 + ((((kc << 2) | lg) ^ swzl) << 3);
                    s16x8 ah = ldf(zbh + idx);
                    s16x8 al = ldf(zbl + idx);
                    mfma16(a0[u],  ah, b1h);
                    mfma16(a1[u],  al, b1h);
                    mfma16(a1[u],  ah, b1l);
                    mfma16(q0h[u], ah, c0h);
                    mfma16(q0l[u], al, c0h);
                    mfma16(q0l[u], ah, c0l);
                    mfma16(q1h[u], ah, c1h);
                    mfma16(q1l[u], al, c1h);
                    mfma16(q1l[u], ah, c1l);
                }
            }
            #pragma unroll
            for (int u = 0; u < 2; u++) {
                const int mt = half * 2 + u;
                #pragma unroll
                for (int r = 0; r < 4; r++) {
                    int m = 16 * mt + 4 * lg + r;
                    float dw0 = np[2 * m] * SQDT_F;
                    float dw1 = np[2 * m + 1] * SQDT_F;
                    float gv0 = fmaf(q0l[u][r], LOINV, q0h[u][r]);
                    float gv1 = fmaf(q1l[u][r], LOINV, q1h[u][r]);
                    sdelta[mt][r] = fmaf(gv0, dw0, gv1 * dw1);
                }
                #pragma unroll
                for (int r = 0; r < 4; r++) {
                    float hv = gelu_exact(fmaf(a1[u][r], LOINV, a0[u][r]));
                    int m = 16 * mt + 4 * lg + r;
                    int idx = m * 128 + (((n0 >> 3) ^ swz(m)) << 3) + (n0 & 7);
                    u16 h = split_hi(hv);
                    hbh[idx] = h;
                    hbl[idx] = split_lo(hv, h);
                }
            }
        }
        __syncthreads();   // bar1: all zb reads done; hb visible

        // p3 — G2: drift = h @ W2 + b2; z += sdelta + drift*dt (z RMW in LDS)
        {
            f32x4 a0[4], a1[4];
            #pragma unroll
            for (int mt = 0; mt < 4; mt++) {
                a0[mt] = f32x4{b20, b20, b20, b20};
                a1[mt] = f32x4{0, 0, 0, 0};
            }
            #pragma unroll
            for (int kc = 0; kc < 4; kc++) {
                int fo = (((wid << 2) | kc) << 10) + (lane << 3);
                s16x8 bh = ldf(wq + W2_OFF + fo);
                s16x8 bl = ldf(wq + W2_OFF + fo + 512);
                #pragma unroll
                for (int mt = 0; mt < 4; mt++) {
                    int idx = (mt * 16 + ln) * 128 + ((((kc << 2) | lg) ^ swzl) << 3);
                    s16x8 ah = ldf(hbh + idx);
                    s16x8 al = ldf(hbl + idx);
                    mfma16(a0[mt], ah, bh);
                    mfma16(a1[mt], al, bh);
                    mfma16(a1[mt], ah, bl);
                }
            }
            #pragma unroll
            for (int mt = 0; mt < 4; mt++)
                #pragma unroll
                for (int r = 0; r < 4; r++) {
                    int m = 16 * mt + 4 * lg + r;
                    int idx = m * 128 + (((n0 >> 3) ^ swz(m)) << 3) + (n0 & 7);
                    float z = fmaf(h2f(zbl[idx]), LOINV, h2f(zbh[idx]));
                    float drift = fmaf(a1[mt][r], LOINV, a0[mt][r]);
                    float v = fmaf(drift, DT_F, z + sdelta[mt][r]);
                    u16 h = split_hi(v);
                    zbh[idx] = h;
                    zbl[idx] = split_lo(v, h);
                }
        }
        __syncthreads();   // bar2: new zb visible
    }

    // ---- decoder: out = z @ dec_w + dec_b ----
    {
        const float bd0 = dec_b[n0];
        f32x4 a0[4], a1[4];
        #pragma unroll
        for (int mt = 0; mt < 4; mt++) {
            a0[mt] = f32x4{bd0, bd0, bd0, bd0};
            a1[mt] = f32x4{0, 0, 0, 0};
        }
        #pragma unroll
        for (int kc = 0; kc < 4; kc++) {
            int fo = (((wid << 2) | kc) << 10) + (lane << 3);
            s16x8 bh = ldf(wpk + DEC_OFF + fo);
            s16x8 bl = ldf(wpk + DEC_OFF + fo + 512);
            #pragma unroll
            for (int mt = 0; mt < 4; mt++) {
                int idx = (mt * 16 + ln) * 128 + ((((kc << 2) | lg) ^ swzl) << 3);
                s16x8 ah = ldf(zbh + idx);
                s16x8 al = ldf(zbl + idx);
                mfma16(a0[mt], ah, bh);
                mfma16(a1[mt], al, bh);
                mfma16(a1[mt], ah, bl);
            }
        }
        #pragma unroll
        for (int mt = 0; mt < 4; mt++)
            #pragma unroll
            for (int r = 0; r < 4; r++) {
                int m = 16 * mt + 4 * lg + r;
                out[(brow + m) * 128 + n0] = fmaf(a1[mt][r], LOINV, a0[mt][r]);
            }
    }
}

extern "C" void kernel_launch(void* const* d_in, const int* in_sizes, int n_in,
                              void* d_out, int out_size, void* d_ws, size_t ws_size,
                              hipStream_t stream) {
    const float* y     = (const float*)d_in[0];
    const float* noise = (const float*)d_in[1];
    const float* enc_w = (const float*)d_in[2];
    const float* enc_b = (const float*)d_in[3];
    const float* mu_w1 = (const float*)d_in[4];
    const float* mu_b1 = (const float*)d_in[5];
    const float* mu_w2 = (const float*)d_in[6];
    const float* mu_b2 = (const float*)d_in[7];
    const float* sig_w = (const float*)d_in[8];
    const float* sig_b = (const float*)d_in[9];
    const float* dec_w = (const float*)d_in[10];
    const float* dec_b = (const float*)d_in[11];
    float* out = (float*)d_out;
    u16* wpk = (u16*)d_ws;

    const int Btot = in_sizes[0] / 128;     // 32768
    prepack<<<(WPK_TOT + 255) / 256, 256, 0, stream>>>(enc_w, mu_w1, mu_w2, sig_w, dec_w, wpk);
    sde_mfma<<<Btot / BR, NT, 0, stream>>>(y, noise, enc_b, mu_b1, mu_b2, sig_b, dec_b,
                                           wpk, out, Btot);
}

// Round 13
// 2880.155 us; speedup vs baseline: 1.0900x; 1.0900x over previous
//
#include <hip/hip_runtime.h>
#include <math.h>

#define NSTEPS 200
#define NT     512          // 8 waves; each wave owns 16 output cols
#define BR     64
#define SQDT_F 0.07071067811865475f
#define DT_F   0.005f
#define LOSCL  4096.0f            // 2^12
#define LOINV  2.44140625e-4f     // 2^-12

typedef float  f32x4 __attribute__((ext_vector_type(4)));
typedef short  s16x8 __attribute__((ext_vector_type(8)));
typedef _Float16 h16x8 __attribute__((ext_vector_type(8)));
typedef unsigned short u16;
typedef unsigned short us4 __attribute__((ext_vector_type(4)));

// prepacked weight offsets in u16 units (each 128x128 matrix = 32768 u16 as hi/lo frags)
#define ENC_OFF 0
#define W1_OFF  32768
#define W2_OFF  65536
#define WG0_OFF 98304
#define WG1_OFF 131072
#define DEC_OFF 163840
#define WPK_TOT 196608

// ---- fp16 scaled two-term split: x ~= hi + lo*2^-12, |err| <= ~2^-23 |x| ----
__device__ __forceinline__ u16 f2h(float v) {
    _Float16 h = (_Float16)v;                       // v_cvt_f16_f32, RNE
    return __builtin_bit_cast(u16, h);
}
__device__ __forceinline__ float h2f(u16 u) {
    return (float)__builtin_bit_cast(_Float16, u);
}
__device__ __forceinline__ u16 split_hi(float v) { return f2h(v); }
__device__ __forceinline__ u16 split_lo(float v, u16 hi) {
    return f2h((v - h2f(hi)) * LOSCL);              // v-hi exact in fp32; *2^12 exact
}
__device__ __forceinline__ float gelu_exact(float x) {
    // exact erf GELU: approx GELU re-rolls the chaotic trajectory (rounds 2/3).
    return 0.5f * x * (1.0f + erff(x * 0.70710678118654752f));
}

// MFMA via builtin: compiler models hazards (r6/r7 inline-asm MFMA NaN'd).
__device__ __forceinline__ void mfma16(f32x4& d, s16x8 a, s16x8 b) {
    d = __builtin_amdgcn_mfma_f32_16x16x32_f16(
            __builtin_bit_cast(h16x8, a), __builtin_bit_cast(h16x8, b), d, 0, 0, 0);
}
__device__ __forceinline__ s16x8 ldf(const u16* p) {
    return *reinterpret_cast<const s16x8*>(p);
}

// LDS swizzle: rows are 256 B apart (bank-aligned); fold row-bit3 into
// chunk-bit1 so rows 4 AND 8 apart spread across banks (r12: conflicts -33%).
__device__ __forceinline__ int swz(int row) {
    return (row & 7) ^ ((row & 8) >> 2);
}

// ---------------- weight prepack: fp32 -> fp16 hi / scaled-lo fragments ----------------
// frag layout: base + ((nt*4 + kc)*2 + term)*512 + lane*8 + i   (u16 units)
// element: B[k = kc*32 + (lane>>4)*8 + i][n = nt*16 + (lane&15)]
// sigma column-deinterleaved: WG0 = sig_w[:,0::2], WG1 = sig_w[:,1::2]
__global__ void prepack(const float* __restrict__ enc_w, const float* __restrict__ mu_w1,
                        const float* __restrict__ mu_w2, const float* __restrict__ sig_w,
                        const float* __restrict__ dec_w, u16* __restrict__ wpk)
{
    int u = blockIdx.x * 256 + threadIdx.x;
    if (u >= WPK_TOT) return;
    int mat  = u >> 15;
    int r    = u & 32767;
    int i    = r & 7;
    int lane = (r >> 3) & 63;
    int term = (r >> 9) & 1;
    int kc   = (r >> 10) & 3;
    int nt   = (r >> 12) & 7;
    int k = kc * 32 + (lane >> 4) * 8 + i;
    int n = nt * 16 + (lane & 15);
    float v;
    switch (mat) {
        case 0:  v = enc_w[k * 128 + n];         break;
        case 1:  v = mu_w1[k * 128 + n];         break;
        case 2:  v = mu_w2[k * 128 + n];         break;
        case 3:  v = sig_w[k * 256 + 2 * n];     break;
        case 4:  v = sig_w[k * 256 + 2 * n + 1]; break;
        default: v = dec_w[k * 128 + n];         break;
    }
    u16 hi = split_hi(v);
    wpk[u] = term ? split_lo(v, hi) : hi;
}

// ---------------- main fused SDE kernel ----------------
// r11 three-pass structure (z read twice from LDS beats W-strips read twice
// from L2 — r12 post-mortem), plus swz() bank fix and sigma unroll 2
// (pipelines the 4x16-reg B-load latency; r12 proved no spill at this
// transient pressure). Established invariants: no resident weights, asm "+s"
// LICM-blocker, z state in LDS hi/lo.
__global__ __launch_bounds__(NT) void sde_mfma(
    const float* __restrict__ y, const float* __restrict__ noise,
    const float* __restrict__ enc_b, const float* __restrict__ mu_b1,
    const float* __restrict__ mu_b2, const float* __restrict__ sig_b,
    const float* __restrict__ dec_b, const u16* __restrict__ wpk,
    float* __restrict__ out, int Btot)
{
    __shared__ __align__(16) u16 zbh[8192];
    __shared__ __align__(16) u16 zbl[8192];
    __shared__ __align__(16) u16 hbh[8192];
    __shared__ __align__(16) u16 hbl[8192];
    __shared__ float nsb[2][128];

    const int tid  = threadIdx.x;
    const int lane = tid & 63, wid = tid >> 6;      // wid 0..7
    const int ln   = lane & 15, lg = lane >> 4;
    const size_t brow = (size_t)blockIdx.x * BR;

    const int n0 = wid * 16 + ln;                   // this thread's single col
    const float b10 = mu_b1[n0];
    const float b20 = mu_b2[n0];
    const float bg0 = sig_b[2 * n0];
    const float bg1 = sig_b[2 * n0 + 1];
    const int swzl = swz(ln);                       // A-read chunk swizzle (row bits 0-3 == ln)

    // ---- stage y into zb (fp16 hi/lo, swizzled) ----
    #pragma unroll
    for (int c = 0; c < 4; c++) {
        int q = c * NT + tid;                 // 0..2047
        int row = q >> 5, k4 = (q & 31) << 2;
        const float4 v = *reinterpret_cast<const float4*>(y + (brow + row) * 128 + k4);
        int idx = row * 128 + (((k4 >> 3) ^ swz(row)) << 3) + (k4 & 7);
        float vv[4] = {v.x, v.y, v.z, v.w};
        us4 hv, lv;
        #pragma unroll
        for (int e = 0; e < 4; e++) {
            u16 h = split_hi(vv[e]);
            u16 l = split_lo(vv[e], h);
            hv[e] = h; lv[e] = l;
        }
        *reinterpret_cast<us4*>(zbh + idx) = hv;
        *reinterpret_cast<us4*>(zbl + idx) = lv;
    }
    __syncthreads();

    // ---- encoder: z0 = gelu_exact(y @ enc_w + enc_b) ----
    float z0v[4][4];
    {
        const float be0 = enc_b[n0];
        f32x4 a0[4], a1[4];
        #pragma unroll
        for (int mt = 0; mt < 4; mt++) {
            a0[mt] = f32x4{be0, be0, be0, be0};
            a1[mt] = f32x4{0, 0, 0, 0};
        }
        #pragma unroll
        for (int kc = 0; kc < 4; kc++) {
            int fo = (((wid << 2) | kc) << 10) + (lane << 3);
            s16x8 bh = ldf(wpk + ENC_OFF + fo);
            s16x8 bl = ldf(wpk + ENC_OFF + fo + 512);
            #pragma unroll
            for (int mt = 0; mt < 4; mt++) {
                int idx = (mt * 16 + ln) * 128 + ((((kc << 2) | lg) ^ swzl) << 3);
                s16x8 ah = ldf(zbh + idx);
                s16x8 al = ldf(zbl + idx);
                mfma16(a0[mt], ah, bh);
                mfma16(a1[mt], al, bh);
                mfma16(a1[mt], ah, bl);
            }
        }
        #pragma unroll
        for (int mt = 0; mt < 4; mt++)
            #pragma unroll
            for (int r = 0; r < 4; r++)
                z0v[mt][r] = gelu_exact(fmaf(a1[mt][r], LOINV, a0[mt][r]));
    }
    __syncthreads();   // all y-tile reads done

    // write z0 into zb; stage noise for t=0
    #pragma unroll
    for (int mt = 0; mt < 4; mt++)
        #pragma unroll
        for (int r = 0; r < 4; r++) {
            int m = 16 * mt + 4 * lg + r;
            int idx = m * 128 + (((n0 >> 3) ^ swz(m)) << 3) + (n0 & 7);
            u16 h = split_hi(z0v[mt][r]);
            zbh[idx] = h;
            zbl[idx] = split_lo(z0v[mt][r], h);
        }
    if (tid < 128) nsb[0][tid] = noise[brow * 2 + tid];
    __syncthreads();

    // loop-opaque weight pointer: defeats LICM hoisting weight loads into
    // loop-carried registers (the scratch-spill source in r5-r10).
    const u16* wq = wpk;

    // ---- 200 Euler-Maruyama steps, 2 barriers each ----
    for (int t = 0; t < NSTEPS; t++) {
        asm volatile("" : "+s"(wq));
        {   // prefetch next step's noise into the other buffer
            int tn = (t + 1 < NSTEPS) ? (t + 1) : t;
            if (tid < 128) nsb[(t + 1) & 1][tid] = noise[((size_t)tn * Btot + brow) * 2 + tid];
        }
        // pass 1 — G1: h = gelu(z @ W1 + b1) -> hb  (W1 from L2)
        {
            f32x4 a0[4], a1[4];
            #pragma unroll
            for (int mt = 0; mt < 4; mt++) {
                a0[mt] = f32x4{b10, b10, b10, b10};
                a1[mt] = f32x4{0, 0, 0, 0};
            }
            #pragma unroll
            for (int kc = 0; kc < 4; kc++) {
                int fo = (((wid << 2) | kc) << 10) + (lane << 3);
                s16x8 bh = ldf(wq + W1_OFF + fo);
                s16x8 bl = ldf(wq + W1_OFF + fo + 512);
                #pragma unroll
                for (int mt = 0; mt < 4; mt++) {
                    int idx = (mt * 16 + ln) * 128 + ((((kc << 2) | lg) ^ swzl) << 3);
                    s16x8 ah = ldf(zbh + idx);
                    s16x8 al = ldf(zbl + idx);
                    mfma16(a0[mt], ah, bh);
                    mfma16(a1[mt], al, bh);
                    mfma16(a1[mt], ah, bl);
                }
            }
            #pragma unroll
            for (int mt = 0; mt < 4; mt++)
                #pragma unroll
                for (int r = 0; r < 4; r++) {
                    float hv = gelu_exact(fmaf(a1[mt][r], LOINV, a0[mt][r]));
                    int m = 16 * mt + 4 * lg + r;
                    int idx = m * 128 + (((n0 >> 3) ^ swz(m)) << 3) + (n0 & 7);
                    u16 h = split_hi(hv);
                    hbh[idx] = h;
                    hbl[idx] = split_lo(hv, h);
                }
        }
        // pass 2 — sigma: sdelta = g0*dw0 + g1*dw1 (Wg0/Wg1 from L2, one A-sweep;
        // unroll 2 pipelines the B-load latency; transient pressure OK per r12)
        float sdelta[4][4];
        {
            f32x4 q0h[4], q0l[4], q1h[4], q1l[4];
            #pragma unroll
            for (int mt = 0; mt < 4; mt++) {
                q0h[mt] = f32x4{bg0, bg0, bg0, bg0}; q0l[mt] = f32x4{0, 0, 0, 0};
                q1h[mt] = f32x4{bg1, bg1, bg1, bg1}; q1l[mt] = f32x4{0, 0, 0, 0};
            }
            #pragma unroll 2
            for (int kc = 0; kc < 4; kc++) {
                int fo = (((wid << 2) | kc) << 10) + (lane << 3);
                s16x8 b0h = ldf(wq + WG0_OFF + fo);
                s16x8 b0l = ldf(wq + WG0_OFF + fo + 512);
                s16x8 b1h = ldf(wq + WG1_OFF + fo);
                s16x8 b1l = ldf(wq + WG1_OFF + fo + 512);
                #pragma unroll
                for (int mt = 0; mt < 4; mt++) {
                    int idx = (mt * 16 + ln) * 128 + ((((kc << 2) | lg) ^ swzl) << 3);
                    s16x8 ah = ldf(zbh + idx);
                    s16x8 al = ldf(zbl + idx);
                    mfma16(q0h[mt], ah, b0h);
                    mfma16(q0l[mt], al, b0h);
                    mfma16(q0l[mt], ah, b0l);
                    mfma16(q1h[mt], ah, b1h);
                    mfma16(q1l[mt], al, b1h);
                    mfma16(q1l[mt], ah, b1l);
                }
            }
            const float* np = nsb[t & 1];
            #pragma unroll
            for (int mt = 0; mt < 4; mt++)
                #pragma unroll
                for (int r = 0; r < 4; r++) {
                    int m = 16 * mt + 4 * lg + r;
                    float dw0 = np[2 * m] * SQDT_F;
                    float dw1 = np[2 * m + 1] * SQDT_F;
                    float gv0 = fmaf(q0l[mt][r], LOINV, q0h[mt][r]);
                    float gv1 = fmaf(q1l[mt][r], LOINV, q1h[mt][r]);
                    sdelta[mt][r] = fmaf(gv0, dw0, gv1 * dw1);
                }
        }
        __syncthreads();   // bar1: all zb reads done; hb visible

        // pass 3 — G2: drift = h @ W2 + b2; z += sdelta + drift*dt (z RMW in LDS)
        {
            f32x4 a0[4], a1[4];
            #pragma unroll
            for (int mt = 0; mt < 4; mt++) {
                a0[mt] = f32x4{b20, b20, b20, b20};
                a1[mt] = f32x4{0, 0, 0, 0};
            }
            #pragma unroll
            for (int kc = 0; kc < 4; kc++) {
                int fo = (((wid << 2) | kc) << 10) + (lane << 3);
                s16x8 bh = ldf(wq + W2_OFF + fo);
                s16x8 bl = ldf(wq + W2_OFF + fo + 512);
                #pragma unroll
                for (int mt = 0; mt < 4; mt++) {
                    int idx = (mt * 16 + ln) * 128 + ((((kc << 2) | lg) ^ swzl) << 3);
                    s16x8 ah = ldf(hbh + idx);
                    s16x8 al = ldf(hbl + idx);
                    mfma16(a0[mt], ah, bh);
                    mfma16(a1[mt], al, bh);
                    mfma16(a1[mt], ah, bl);
                }
            }
            #pragma unroll
            for (int mt = 0; mt < 4; mt++)
                #pragma unroll
                for (int r = 0; r < 4; r++) {
                    int m = 16 * mt + 4 * lg + r;
                    int idx = m * 128 + (((n0 >> 3) ^ swz(m)) << 3) + (n0 & 7);
                    float z = fmaf(h2f(zbl[idx]), LOINV, h2f(zbh[idx]));
                    float drift = fmaf(a1[mt][r], LOINV, a0[mt][r]);
                    float v = fmaf(drift, DT_F, z + sdelta[mt][r]);
                    u16 h = split_hi(v);
                    zbh[idx] = h;
                    zbl[idx] = split_lo(v, h);
                }
        }
        __syncthreads();   // bar2: new zb visible
    }

    // ---- decoder: out = z @ dec_w + dec_b ----
    {
        const float bd0 = dec_b[n0];
        f32x4 a0[4], a1[4];
        #pragma unroll
        for (int mt = 0; mt < 4; mt++) {
            a0[mt] = f32x4{bd0, bd0, bd0, bd0};
            a1[mt] = f32x4{0, 0, 0, 0};
        }
        #pragma unroll
        for (int kc = 0; kc < 4; kc++) {
            int fo = (((wid << 2) | kc) << 10) + (lane << 3);
            s16x8 bh = ldf(wpk + DEC_OFF + fo);
            s16x8 bl = ldf(wpk + DEC_OFF + fo + 512);
            #pragma unroll
            for (int mt = 0; mt < 4; mt++) {
                int idx = (mt * 16 + ln) * 128 + ((((kc << 2) | lg) ^ swzl) << 3);
                s16x8 ah = ldf(zbh + idx);
                s16x8 al = ldf(zbl + idx);
                mfma16(a0[mt], ah, bh);
                mfma16(a1[mt], al, bh);
                mfma16(a1[mt], ah, bl);
            }
        }
        #pragma unroll
        for (int mt = 0; mt < 4; mt++)
            #pragma unroll
            for (int r = 0; r < 4; r++) {
                int m = 16 * mt + 4 * lg + r;
                out[(brow + m) * 128 + n0] = fmaf(a1[mt][r], LOINV, a0[mt][r]);
            }
    }
}

extern "C" void kernel_launch(void* const* d_in, const int* in_sizes, int n_in,
                              void* d_out, int out_size, void* d_ws, size_t ws_size,
                              hipStream_t stream) {
    const float* y     = (const float*)d_in[0];
    const float* noise = (const float*)d_in[1];
    const float* enc_w = (const float*)d_in[2];
    const float* enc_b = (const float*)d_in[3];
    const float* mu_w1 = (const float*)d_in[4];
    const float* mu_b1 = (const float*)d_in[5];
    const float* mu_w2 = (const float*)d_in[6];
    const float* mu_b2 = (const float*)d_in[7];
    const float* sig_w = (const float*)d_in[8];
    const float* sig_b = (const float*)d_in[9];
    const float* dec_w = (const float*)d_in[10];
    const float* dec_b = (const float*)d_in[11];
    float* out = (float*)d_out;
    u16* wpk = (u16*)d_ws;

    const int Btot = in_sizes[0] / 128;     // 32768
    prepack<<<(WPK_TOT + 255) / 256, 256, 0, stream>>>(enc_w, mu_w1, mu_w2, sig_w, dec_w, wpk);
    sde_mfma<<<Btot / BR, NT, 0, stream>>>(y, noise, enc_b, mu_b1, mu_b2, sig_b, dec_b,
                                           wpk, out, Btot);
}

// Round 14
// 2874.239 us; speedup vs baseline: 1.0922x; 1.0021x over previous
//
#include <hip/hip_runtime.h>
#include <math.h>

#define NSTEPS 200
#define NT     512          // 8 waves; each wave owns 16 output cols
#define BR     64
#define SQDT_F 0.07071067811865475f
#define DT_F   0.005f
#define LOSCL  4096.0f            // 2^12
#define LOINV  2.44140625e-4f     // 2^-12

typedef float  f32x4 __attribute__((ext_vector_type(4)));
typedef short  s16x8 __attribute__((ext_vector_type(8)));
typedef _Float16 h16x8 __attribute__((ext_vector_type(8)));
typedef unsigned short u16;
typedef unsigned short us4 __attribute__((ext_vector_type(4)));

// prepacked weight offsets in u16 units (each 128x128 matrix = 32768 u16 as hi/lo frags)
#define ENC_OFF 0
#define W1_OFF  32768
#define W2_OFF  65536
#define WG0_OFF 98304
#define WG1_OFF 131072
#define DEC_OFF 163840
#define WPK_TOT 196608

// ---- fp16 scaled two-term split: x ~= hi + lo*2^-12, |err| <= ~2^-23 |x| ----
__device__ __forceinline__ u16 f2h(float v) {
    _Float16 h = (_Float16)v;                       // v_cvt_f16_f32, RNE
    return __builtin_bit_cast(u16, h);
}
__device__ __forceinline__ float h2f(u16 u) {
    return (float)__builtin_bit_cast(_Float16, u);
}
__device__ __forceinline__ u16 split_hi(float v) { return f2h(v); }
__device__ __forceinline__ u16 split_lo(float v, u16 hi) {
    return f2h((v - h2f(hi)) * LOSCL);              // v-hi exact in fp32; *2^12 exact
}

// GELU via Abramowitz-Stegun 7.1.26 erf: max abs err 1.5e-7 on erf — below
// the fp16-split noise floor (1.2e-7) that already passes at absmax 0.0078,
// and 7000x tighter than the tanh-GELU that failed r2 (1e-3). ~15 VALU ops
// vs ~35 for libm erff (the largest VALU item: 16 calls/thread/step).
__device__ __forceinline__ float gelu_fast(float x) {
    float ax = fabsf(x) * 0.70710678118654752f;     // |x|/sqrt(2)
    float t  = __builtin_amdgcn_rcpf(fmaf(0.3275911f, ax, 1.0f));   // ~1ulp rcp
    float p  = fmaf(t, 1.061405429f, -1.453152027f);
    p = fmaf(t, p, 1.421413741f);
    p = fmaf(t, p, -0.284496736f);
    p = fmaf(t, p, 0.254829592f);
    p = p * t;
    float e  = __expf(-ax * ax);                    // v_exp_f32 path, ~1ulp
    float er = fmaf(-p, e, 1.0f);                   // erf(|x|/sqrt2)
    er = copysignf(er, x);
    return 0.5f * x * (1.0f + er);
}

// MFMA via builtin: compiler models hazards (r6/r7 inline-asm MFMA NaN'd).
__device__ __forceinline__ void mfma16(f32x4& d, s16x8 a, s16x8 b) {
    d = __builtin_amdgcn_mfma_f32_16x16x32_f16(
            __builtin_bit_cast(h16x8, a), __builtin_bit_cast(h16x8, b), d, 0, 0, 0);
}
__device__ __forceinline__ s16x8 ldf(const u16* p) {
    return *reinterpret_cast<const s16x8*>(p);
}

// LDS chunk swizzle (kept from r12/r13; conflicts proved b128-inherent, but
// this is the layout all sites agree on).
__device__ __forceinline__ int swz(int row) {
    return (row & 7) ^ ((row & 8) >> 2);
}

// ---------------- weight prepack: fp32 -> fp16 hi / scaled-lo fragments ----------------
// frag layout: base + ((nt*4 + kc)*2 + term)*512 + lane*8 + i   (u16 units)
// element: B[k = kc*32 + (lane>>4)*8 + i][n = nt*16 + (lane&15)]
// sigma column-deinterleaved: WG0 = sig_w[:,0::2], WG1 = sig_w[:,1::2]
__global__ void prepack(const float* __restrict__ enc_w, const float* __restrict__ mu_w1,
                        const float* __restrict__ mu_w2, const float* __restrict__ sig_w,
                        const float* __restrict__ dec_w, u16* __restrict__ wpk)
{
    int u = blockIdx.x * 256 + threadIdx.x;
    if (u >= WPK_TOT) return;
    int mat  = u >> 15;
    int r    = u & 32767;
    int i    = r & 7;
    int lane = (r >> 3) & 63;
    int term = (r >> 9) & 1;
    int kc   = (r >> 10) & 3;
    int nt   = (r >> 12) & 7;
    int k = kc * 32 + (lane >> 4) * 8 + i;
    int n = nt * 16 + (lane & 15);
    float v;
    switch (mat) {
        case 0:  v = enc_w[k * 128 + n];         break;
        case 1:  v = mu_w1[k * 128 + n];         break;
        case 2:  v = mu_w2[k * 128 + n];         break;
        case 3:  v = sig_w[k * 256 + 2 * n];     break;
        case 4:  v = sig_w[k * 256 + 2 * n + 1]; break;
        default: v = dec_w[k * 128 + n];         break;
    }
    u16 hi = split_hi(v);
    wpk[u] = term ? split_lo(v, hi) : hi;
}

// ---------------- main fused SDE kernel ----------------
// r13 three-pass structure + r14 deltas:
//  - zr[4][4] carried in regs across steps (replaces sdelta carry, same 16
//    regs; kills pass-3's 16 scalar LDS reads + reconstruct; z accumulates
//    in full fp32 like passing r8)
//  - A&S-erf GELU (largest VALU item halved)
// Established invariants: no resident weights (L2 B-frags), asm "+s"
// LICM-blocker, MFMA builtin, fp16 hi/lo split state in LDS.
__global__ __launch_bounds__(NT) void sde_mfma(
    const float* __restrict__ y, const float* __restrict__ noise,
    const float* __restrict__ enc_b, const float* __restrict__ mu_b1,
    const float* __restrict__ mu_b2, const float* __restrict__ sig_b,
    const float* __restrict__ dec_b, const u16* __restrict__ wpk,
    float* __restrict__ out, int Btot)
{
    __shared__ __align__(16) u16 zbh[8192];
    __shared__ __align__(16) u16 zbl[8192];
    __shared__ __align__(16) u16 hbh[8192];
    __shared__ __align__(16) u16 hbl[8192];
    __shared__ float nsb[2][128];

    const int tid  = threadIdx.x;
    const int lane = tid & 63, wid = tid >> 6;      // wid 0..7
    const int ln   = lane & 15, lg = lane >> 4;
    const size_t brow = (size_t)blockIdx.x * BR;

    const int n0 = wid * 16 + ln;                   // this thread's single col
    const float b10 = mu_b1[n0];
    const float b20 = mu_b2[n0];
    const float bg0 = sig_b[2 * n0];
    const float bg1 = sig_b[2 * n0 + 1];
    const int swzl = swz(ln);                       // A-read chunk swizzle

    // ---- stage y into zb (fp16 hi/lo, swizzled) ----
    #pragma unroll
    for (int c = 0; c < 4; c++) {
        int q = c * NT + tid;                 // 0..2047
        int row = q >> 5, k4 = (q & 31) << 2;
        const float4 v = *reinterpret_cast<const float4*>(y + (brow + row) * 128 + k4);
        int idx = row * 128 + (((k4 >> 3) ^ swz(row)) << 3) + (k4 & 7);
        float vv[4] = {v.x, v.y, v.z, v.w};
        us4 hv, lv;
        #pragma unroll
        for (int e = 0; e < 4; e++) {
            u16 h = split_hi(vv[e]);
            u16 l = split_lo(vv[e], h);
            hv[e] = h; lv[e] = l;
        }
        *reinterpret_cast<us4*>(zbh + idx) = hv;
        *reinterpret_cast<us4*>(zbl + idx) = lv;
    }
    __syncthreads();

    float zr[4][4];   // z state, fp32, carried across all 200 steps

    // ---- encoder: z0 = gelu(y @ enc_w + enc_b) ----
    {
        const float be0 = enc_b[n0];
        f32x4 a0[4], a1[4];
        #pragma unroll
        for (int mt = 0; mt < 4; mt++) {
            a0[mt] = f32x4{be0, be0, be0, be0};
            a1[mt] = f32x4{0, 0, 0, 0};
        }
        #pragma unroll
        for (int kc = 0; kc < 4; kc++) {
            int fo = (((wid << 2) | kc) << 10) + (lane << 3);
            s16x8 bh = ldf(wpk + ENC_OFF + fo);
            s16x8 bl = ldf(wpk + ENC_OFF + fo + 512);
            #pragma unroll
            for (int mt = 0; mt < 4; mt++) {
                int idx = (mt * 16 + ln) * 128 + ((((kc << 2) | lg) ^ swzl) << 3);
                s16x8 ah = ldf(zbh + idx);
                s16x8 al = ldf(zbl + idx);
                mfma16(a0[mt], ah, bh);
                mfma16(a1[mt], al, bh);
                mfma16(a1[mt], ah, bl);
            }
        }
        #pragma unroll
        for (int mt = 0; mt < 4; mt++)
            #pragma unroll
            for (int r = 0; r < 4; r++)
                zr[mt][r] = gelu_fast(fmaf(a1[mt][r], LOINV, a0[mt][r]));
    }
    __syncthreads();   // all y-tile reads done

    // write z0 into zb; stage noise for t=0
    #pragma unroll
    for (int mt = 0; mt < 4; mt++)
        #pragma unroll
        for (int r = 0; r < 4; r++) {
            int m = 16 * mt + 4 * lg + r;
            int idx = m * 128 + (((n0 >> 3) ^ swz(m)) << 3) + (n0 & 7);
            u16 h = split_hi(zr[mt][r]);
            zbh[idx] = h;
            zbl[idx] = split_lo(zr[mt][r], h);
        }
    if (tid < 128) nsb[0][tid] = noise[brow * 2 + tid];
    __syncthreads();

    // loop-opaque weight pointer: defeats LICM hoisting weight loads into
    // loop-carried registers (the scratch-spill source in r5-r10).
    const u16* wq = wpk;

    // ---- 200 Euler-Maruyama steps, 2 barriers each ----
    for (int t = 0; t < NSTEPS; t++) {
        asm volatile("" : "+s"(wq));
        {   // prefetch next step's noise into the other buffer
            int tn = (t + 1 < NSTEPS) ? (t + 1) : t;
            if (tid < 128) nsb[(t + 1) & 1][tid] = noise[((size_t)tn * Btot + brow) * 2 + tid];
        }
        // pass 1 — G1: h = gelu(z @ W1 + b1) -> hb  (W1 from L2)
        {
            f32x4 a0[4], a1[4];
            #pragma unroll
            for (int mt = 0; mt < 4; mt++) {
                a0[mt] = f32x4{b10, b10, b10, b10};
                a1[mt] = f32x4{0, 0, 0, 0};
            }
            #pragma unroll
            for (int kc = 0; kc < 4; kc++) {
                int fo = (((wid << 2) | kc) << 10) + (lane << 3);
                s16x8 bh = ldf(wq + W1_OFF + fo);
                s16x8 bl = ldf(wq + W1_OFF + fo + 512);
                #pragma unroll
                for (int mt = 0; mt < 4; mt++) {
                    int idx = (mt * 16 + ln) * 128 + ((((kc << 2) | lg) ^ swzl) << 3);
                    s16x8 ah = ldf(zbh + idx);
                    s16x8 al = ldf(zbl + idx);
                    mfma16(a0[mt], ah, bh);
                    mfma16(a1[mt], al, bh);
                    mfma16(a1[mt], ah, bl);
                }
            }
            #pragma unroll
            for (int mt = 0; mt < 4; mt++)
                #pragma unroll
                for (int r = 0; r < 4; r++) {
                    float hv = gelu_fast(fmaf(a1[mt][r], LOINV, a0[mt][r]));
                    int m = 16 * mt + 4 * lg + r;
                    int idx = m * 128 + (((n0 >> 3) ^ swz(m)) << 3) + (n0 & 7);
                    u16 h = split_hi(hv);
                    hbh[idx] = h;
                    hbl[idx] = split_lo(hv, h);
                }
        }
        // pass 2 — sigma: zr += g0*dw0 + g1*dw1 (Wg0/Wg1 from L2, one A-sweep;
        // unroll 2 pipelines the B-load latency)
        {
            f32x4 q0h[4], q0l[4], q1h[4], q1l[4];
            #pragma unroll
            for (int mt = 0; mt < 4; mt++) {
                q0h[mt] = f32x4{bg0, bg0, bg0, bg0}; q0l[mt] = f32x4{0, 0, 0, 0};
                q1h[mt] = f32x4{bg1, bg1, bg1, bg1}; q1l[mt] = f32x4{0, 0, 0, 0};
            }
            #pragma unroll 2
            for (int kc = 0; kc < 4; kc++) {
                int fo = (((wid << 2) | kc) << 10) + (lane << 3);
                s16x8 b0h = ldf(wq + WG0_OFF + fo);
                s16x8 b0l = ldf(wq + WG0_OFF + fo + 512);
                s16x8 b1h = ldf(wq + WG1_OFF + fo);
                s16x8 b1l = ldf(wq + WG1_OFF + fo + 512);
                #pragma unroll
                for (int mt = 0; mt < 4; mt++) {
                    int idx = (mt * 16 + ln) * 128 + ((((kc << 2) | lg) ^ swzl) << 3);
                    s16x8 ah = ldf(zbh + idx);
                    s16x8 al = ldf(zbl + idx);
                    mfma16(q0h[mt], ah, b0h);
                    mfma16(q0l[mt], al, b0h);
                    mfma16(q0l[mt], ah, b0l);
                    mfma16(q1h[mt], ah, b1h);
                    mfma16(q1l[mt], al, b1h);
                    mfma16(q1l[mt], ah, b1l);
                }
            }
            const float* np = nsb[t & 1];
            #pragma unroll
            for (int mt = 0; mt < 4; mt++)
                #pragma unroll
                for (int r = 0; r < 4; r++) {
                    int m = 16 * mt + 4 * lg + r;
                    float dw0 = np[2 * m] * SQDT_F;
                    float dw1 = np[2 * m + 1] * SQDT_F;
                    float gv0 = fmaf(q0l[mt][r], LOINV, q0h[mt][r]);
                    float gv1 = fmaf(q1l[mt][r], LOINV, q1h[mt][r]);
                    zr[mt][r] = fmaf(gv0, dw0, fmaf(gv1, dw1, zr[mt][r]));
                }
        }
        __syncthreads();   // bar1: all zb reads done; hb visible

        // pass 3 — G2: drift = h @ W2 + b2; zr += drift*dt; rewrite zb
        {
            f32x4 a0[4], a1[4];
            #pragma unroll
            for (int mt = 0; mt < 4; mt++) {
                a0[mt] = f32x4{b20, b20, b20, b20};
                a1[mt] = f32x4{0, 0, 0, 0};
            }
            #pragma unroll
            for (int kc = 0; kc < 4; kc++) {
                int fo = (((wid << 2) | kc) << 10) + (lane << 3);
                s16x8 bh = ldf(wq + W2_OFF + fo);
                s16x8 bl = ldf(wq + W2_OFF + fo + 512);
                #pragma unroll
                for (int mt = 0; mt < 4; mt++) {
                    int idx = (mt * 16 + ln) * 128 + ((((kc << 2) | lg) ^ swzl) << 3);
                    s16x8 ah = ldf(hbh + idx);
                    s16x8 al = ldf(hbl + idx);
                    mfma16(a0[mt], ah, bh);
                    mfma16(a1[mt], al, bh);
                    mfma16(a1[mt], ah, bl);
                }
            }
            #pragma unroll
            for (int mt = 0; mt < 4; mt++)
                #pragma unroll
                for (int r = 0; r < 4; r++) {
                    float drift = fmaf(a1[mt][r], LOINV, a0[mt][r]);
                    float v = fmaf(drift, DT_F, zr[mt][r]);
                    zr[mt][r] = v;
                    int m = 16 * mt + 4 * lg + r;
                    int idx = m * 128 + (((n0 >> 3) ^ swz(m)) << 3) + (n0 & 7);
                    u16 h = split_hi(v);
                    zbh[idx] = h;
                    zbl[idx] = split_lo(v, h);
                }
        }
        __syncthreads();   // bar2: new zb visible
    }

    // ---- decoder: out = z @ dec_w + dec_b ----
    {
        const float bd0 = dec_b[n0];
        f32x4 a0[4], a1[4];
        #pragma unroll
        for (int mt = 0; mt < 4; mt++) {
            a0[mt] = f32x4{bd0, bd0, bd0, bd0};
            a1[mt] = f32x4{0, 0, 0, 0};
        }
        #pragma unroll
        for (int kc = 0; kc < 4; kc++) {
            int fo = (((wid << 2) | kc) << 10) + (lane << 3);
            s16x8 bh = ldf(wpk + DEC_OFF + fo);
            s16x8 bl = ldf(wpk + DEC_OFF + fo + 512);
            #pragma unroll
            for (int mt = 0; mt < 4; mt++) {
                int idx = (mt * 16 + ln) * 128 + ((((kc << 2) | lg) ^ swzl) << 3);
                s16x8 ah = ldf(zbh + idx);
                s16x8 al = ldf(zbl + idx);
                mfma16(a0[mt], ah, bh);
                mfma16(a1[mt], al, bh);
                mfma16(a1[mt], ah, bl);
            }
        }
        #pragma unroll
        for (int mt = 0; mt < 4; mt++)
            #pragma unroll
            for (int r = 0; r < 4; r++) {
                int m = 16 * mt + 4 * lg + r;
                out[(brow + m) * 128 + n0] = fmaf(a1[mt][r], LOINV, a0[mt][r]);
            }
    }
}

extern "C" void kernel_launch(void* const* d_in, const int* in_sizes, int n_in,
                              void* d_out, int out_size, void* d_ws, size_t ws_size,
                              hipStream_t stream) {
    const float* y     = (const float*)d_in[0];
    const float* noise = (const float*)d_in[1];
    const float* enc_w = (const float*)d_in[2];
    const float* enc_b = (const float*)d_in[3];
    const float* mu_w1 = (const float*)d_in[4];
    const float* mu_b1 = (const float*)d_in[5];
    const float* mu_w2 = (const float*)d_in[6];
    const float* mu_b2 = (const float*)d_in[7];
    const float* sig_w = (const float*)d_in[8];
    const float* sig_b = (const float*)d_in[9];
    const float* dec_w = (const float*)d_in[10];
    const float* dec_b = (const float*)d_in[11];
    float* out = (float*)d_out;
    u16* wpk = (u16*)d_ws;

    const int Btot = in_sizes[0] / 128;     // 32768
    prepack<<<(WPK_TOT + 255) / 256, 256, 0, stream>>>(enc_w, mu_w1, mu_w2, sig_w, dec_w, wpk);
    sde_mfma<<<Btot / BR, NT, 0, stream>>>(y, noise, enc_b, mu_b1, mu_b2, sig_b, dec_b,
                                           wpk, out, Btot);
}